// Round 9
// baseline (346.818 us; speedup 1.0000x reference)
//
#include <hip/hip_runtime.h>
#include <hip/hip_bf16.h>
#include <math.h>

#define N_NODES 10000
#define N_EDGES 640000
#define N_GRAPHS 64
#define DIM 128
#define NEG_SLOPE 0.01f
#define NB_CSR 128            // CSR partitions AND blocks of the fused CSR kernel
#define EDGES_PER_BLK (N_EDGES / NB_CSR)

typedef __attribute__((ext_vector_type(8))) short bf16x8;
typedef __attribute__((ext_vector_type(4))) float f32x4;

// ---------------- workspace layout (bytes) ----------------
// resid_b16 : 0          .. 5,120,000    bf16[2][10000][128]
// a_self    : 5,120,000  .. 5,200,000    float[2][10000]
// a_nb      : 5,200,000  .. 5,280,000    float[2][10000]
// deg       : 5,280,000  .. 5,320,000    int[10000]
// rowptr    : 5,320,000  .. 5,360,004    int[10001]
// barriers  : 5,360,008  .. 5,360,024    int[3] (memset to 0 every call)
// csr_src   : 5,360,032  .. 7,920,032    int[640000]
// feat_b16  : 7,920,032  .. 13,040,032   bf16[2][10000][128]
// bh        : 13,040,032 .. 18,160,032   int[128][10000]

__device__ __forceinline__ unsigned short f2bf(float f) {
    __hip_bfloat16 h = __float2bfloat16(f);
    return *reinterpret_cast<unsigned short*>(&h);
}

// Device-scope grid barrier. Counters are zeroed by hipMemsetAsync before the
// launch. Co-residency of all NB_CSR blocks is guaranteed by construction
// (128 blocks x 16 waves, 44KB LDS: wave-limit 2 blocks/CU -> needs >=64 of
// 256 CUs; CP dispatches greedily, nothing else runs on the stream).
__device__ __forceinline__ void grid_barrier(int* __restrict__ bar, int idx) {
    __syncthreads();
    if (threadIdx.x == 0) {
        __threadfence();  // release: prior writes visible device-wide
        __hip_atomic_fetch_add(&bar[idx], 1, __ATOMIC_ACQ_REL,
                               __HIP_MEMORY_SCOPE_AGENT);
        while (__hip_atomic_load(&bar[idx], __ATOMIC_ACQUIRE,
                                 __HIP_MEMORY_SCOPE_AGENT) < NB_CSR) {
            __builtin_amdgcn_s_sleep(8);
        }
        __threadfence();  // acquire: invalidate stale caches before re-reads
    }
    __syncthreads();
}

// ---------------- fused CSR build: hist -> node-scan -> rowptr -> scatter ----------
__global__ __launch_bounds__(1024) void csr_fused(
    const int4* __restrict__ esrc4, const int4* __restrict__ edst4,
    int* __restrict__ bh, int* __restrict__ deg, int* __restrict__ rowptr,
    int* __restrict__ csr_src, float* __restrict__ phis, int* __restrict__ bar) {
    __shared__ int lds[N_NODES];   // 40KB: hist in P1, cursors in P3
    __shared__ int sdata[1024];    // scan_deg scratch (block 0)
    const int blk = blockIdx.x;
    const int t = threadIdx.x;
    const int base4 = blk * (EDGES_PER_BLK / 4);

    // ---- P1: per-partition LDS histogram ----
    for (int n = t; n < N_NODES; n += 1024) lds[n] = 0;
    __syncthreads();
    for (int i = t; i < EDGES_PER_BLK / 4; i += 1024) {
        int4 d = edst4[base4 + i];
        atomicAdd(&lds[d.x], 1);
        atomicAdd(&lds[d.y], 1);
        atomicAdd(&lds[d.z], 1);
        atomicAdd(&lds[d.w], 1);
    }
    __syncthreads();
    {
        int* dst = bh + (size_t)blk * N_NODES;
        for (int n = t; n < N_NODES; n += 1024) dst[n] = lds[n];
    }
    grid_barrier(bar, 0);

    // ---- P2a: per-node exclusive scan over partitions (blocks 0-2) + phis zero ----
    {
        int g = blk * 1024 + t;                 // int4 group of 4 nodes
        if (g < N_NODES / 4) {
            int4 run = {0, 0, 0, 0};
            for (int p = 0; p < NB_CSR; ++p) {
                int4* pp = reinterpret_cast<int4*>(bh + (size_t)p * N_NODES) + g;
                int4 v = *pp;
                *pp = run;
                run.x += v.x; run.y += v.y; run.z += v.z; run.w += v.w;
            }
            reinterpret_cast<int4*>(deg)[g] = run;
        }
        int z = g - 3 * 1024;                   // blocks 3..18 zero phis
        if (z >= 0 && z < N_GRAPHS * 2 * DIM) phis[z] = 0.f;
    }
    grid_barrier(bar, 1);

    // ---- P2b: rowptr scan (block 0 only) ----
    if (blk == 0) {
        const int base = t * 10;
        int cnt = N_NODES - base;
        if (cnt < 0) cnt = 0;
        if (cnt > 10) cnt = 10;
        int local[10];
        int s = 0;
        for (int i = 0; i < cnt; ++i) { local[i] = s; s += deg[base + i]; }
        sdata[t] = s;
        __syncthreads();
        for (int off = 1; off < 1024; off <<= 1) {
            int v = 0;
            if (t >= off) v = sdata[t - off];
            __syncthreads();
            if (t >= off) sdata[t] += v;
            __syncthreads();
        }
        int pre = (t == 0) ? 0 : sdata[t - 1];
        for (int i = 0; i < cnt; ++i) rowptr[base + i] = pre + local[i];
        if (t == 1023) rowptr[N_NODES] = sdata[1023];
    }
    grid_barrier(bar, 2);

    // ---- P3: scatter via LDS cursors ----
    {
        const int* boff = bh + (size_t)blk * N_NODES;
        for (int n = t; n < N_NODES; n += 1024) lds[n] = rowptr[n] + boff[n];
        __syncthreads();
        for (int i = t; i < EDGES_PER_BLK / 4; i += 1024) {
            int4 s = esrc4[base4 + i];
            int4 d = edst4[base4 + i];
            csr_src[atomicAdd(&lds[d.x], 1)] = s.x;
            csr_src[atomicAdd(&lds[d.y], 1)] = s.y;
            csr_src[atomicAdd(&lds[d.z], 1)] = s.z;
            csr_src[atomicAdd(&lds[d.w], 1)] = s.w;
        }
    }
}

// ---------------- MFMA GEMM: 64 nodes x 128 cols, K=128, bf16 ----------------
// grid (157, 4), block 256. y: bit0 = which (0=feat,1=resid), bit1 = b.
// which==0: feat_b16 + direct a_self/a_nb stores (full 128 cols per block).
// which==1: resid_b16.
__global__ __launch_bounds__(256) void gemm_mfma(
    const float* __restrict__ x, const float* __restrict__ Wfc,
    const float* __restrict__ bfc, const float* __restrict__ Wres,
    const float* __restrict__ wl, const float* __restrict__ wr,
    unsigned short* __restrict__ resid_b16, unsigned short* __restrict__ feat_b16,
    float* __restrict__ a_self, float* __restrict__ a_nb) {
    const int which = blockIdx.y & 1;
    const int b = blockIdx.y >> 1;
    const float* __restrict__ W = (which ? Wres : Wfc) + b * DIM * DIM;
    const int n0 = blockIdx.x * 64;
    const int t = threadIdx.x;

    __shared__ unsigned short xs[64][136];
    __shared__ unsigned short wsh[128][136];

    // stage x tile -> bf16 LDS (4 threads/row, 32 cols each)
    {
        const int r = t >> 2, qq = t & 3;
        const int n = n0 + r;
        ushort4* drow = reinterpret_cast<ushort4*>(&xs[r][qq * 32]);
        if (n < N_NODES) {
            const float4* p = reinterpret_cast<const float4*>(x + (size_t)n * DIM + qq * 32);
#pragma unroll
            for (int i = 0; i < 8; ++i) {
                float4 v = p[i];
                ushort4 u;
                u.x = f2bf(v.x); u.y = f2bf(v.y); u.z = f2bf(v.z); u.w = f2bf(v.w);
                drow[i] = u;
            }
        } else {
            ushort4 z = {0, 0, 0, 0};
#pragma unroll
            for (int i = 0; i < 8; ++i) drow[i] = z;
        }
    }
    // stage W -> bf16 LDS (2 threads/row, 64 cols each)
    {
        const int rw = t >> 1, hh = t & 1;
        const float4* p = reinterpret_cast<const float4*>(W + (size_t)rw * DIM + hh * 64);
        ushort4* drow = reinterpret_cast<ushort4*>(&wsh[rw][hh * 64]);
#pragma unroll
        for (int i = 0; i < 16; ++i) {
            float4 v = p[i];
            ushort4 u;
            u.x = f2bf(v.x); u.y = f2bf(v.y); u.z = f2bf(v.z); u.w = f2bf(v.w);
            drow[i] = u;
        }
    }
    __syncthreads();

    const int wave = t >> 6, lane = t & 63;
    const int quad = lane >> 4, jc = lane & 15;
    const int m0 = wave * 16;

    bf16x8 af[4];
#pragma unroll
    for (int ks = 0; ks < 4; ++ks)
        af[ks] = *reinterpret_cast<const bf16x8*>(&xs[m0 + jc][ks * 32 + quad * 8]);

    f32x4 accs[8];
    float ps[4] = {0.f, 0.f, 0.f, 0.f}, pr[4] = {0.f, 0.f, 0.f, 0.f};
#pragma unroll
    for (int jt = 0; jt < 8; ++jt) {
        f32x4 acc = {0.f, 0.f, 0.f, 0.f};
#pragma unroll
        for (int ks = 0; ks < 4; ++ks) {
            bf16x8 bfr = *reinterpret_cast<const bf16x8*>(
                &wsh[jt * 16 + jc][ks * 32 + quad * 8]);
            acc = __builtin_amdgcn_mfma_f32_16x16x32_bf16(af[ks], bfr, acc, 0, 0, 0);
        }
        if (!which) {
            float bias = bfc[b * DIM + jt * 16 + jc];
            acc[0] += bias; acc[1] += bias; acc[2] += bias; acc[3] += bias;
            float wlv = wl[b * DIM + jt * 16 + jc];
            float wrv = wr[b * DIM + jt * 16 + jc];
#pragma unroll
            for (int r2 = 0; r2 < 4; ++r2) { ps[r2] += acc[r2] * wlv; pr[r2] += acc[r2] * wrv; }
        }
        accs[jt] = acc;
    }

    __syncthreads();  // all waves done reading xs/wsh

    if (!which) {
        // a_self/a_nb: reduce over the 16 j-lanes (full 128 cols in this block)
#pragma unroll
        for (int off = 8; off > 0; off >>= 1) {
#pragma unroll
            for (int r2 = 0; r2 < 4; ++r2) {
                ps[r2] += __shfl_xor(ps[r2], off, 64);
                pr[r2] += __shfl_xor(pr[r2], off, 64);
            }
        }
        if (jc == 0) {
#pragma unroll
            for (int r2 = 0; r2 < 4; ++r2) {
                int n = n0 + m0 + quad * 4 + r2;
                if (n < N_NODES) {
                    a_self[b * N_NODES + n] = ps[r2];
                    a_nb[b * N_NODES + n] = pr[r2];
                }
            }
        }
    }

    // stage bf16 output into xs, then coalesced store
    unsigned short* __restrict__ dstb = which ? resid_b16 : feat_b16;
#pragma unroll
    for (int jt = 0; jt < 8; ++jt)
#pragma unroll
        for (int r2 = 0; r2 < 4; ++r2)
            xs[m0 + quad * 4 + r2][jt * 16 + jc] = f2bf(accs[jt][r2]);
    __syncthreads();
    {
        const int r = t >> 2, qq = t & 3;
        const int n = n0 + r;
        if (n < N_NODES) {
            uint4* dst = reinterpret_cast<uint4*>(
                dstb + ((size_t)b * N_NODES + n) * DIM + qq * 32);
            const uint4* srcp = reinterpret_cast<const uint4*>(&xs[r][qq * 32]);
#pragma unroll
            for (int i = 0; i < 4; ++i) dst[i] = srcp[i];
        }
    }
}

// ---------------- softmax + weighted aggregation + residual + relu ----------------
// grid (2500, 2), block 256 = 4 waves, one node per wave. Single pass (scores
// |s| < ~20 << 88 -> exp(s) safe in fp32; softmax shift-invariant).
// Depth-3 pipeline: two gathers resident, a third issued before consuming.
__global__ __launch_bounds__(256) void aggregate(
    const unsigned short* __restrict__ feat_b16,
    const unsigned short* __restrict__ resid_b16,
    const float* __restrict__ a_self, const float* __restrict__ a_nb,
    const int* __restrict__ rowptr, const int* __restrict__ csr_src,
    float* __restrict__ out) {
    const int wave = threadIdx.x >> 6;
    const int lane = threadIdx.x & 63;
    const int n = blockIdx.x * 4 + wave;
    const int b = blockIdx.y;
    const int q = lane >> 4;     // edge slot within group of 4
    const int l16 = lane & 15;   // covers channels [l16*8, l16*8+8)
    const int start = rowptr[n];
    const int end = rowptr[n + 1];

    const float* __restrict__ anb = a_nb + b * N_NODES;
    const uint4* __restrict__ fb =
        reinterpret_cast<const uint4*>(feat_b16 + (size_t)b * N_NODES * DIM);
    const float asl = a_self[b * N_NODES + n];

    float acc[8];
#pragma unroll
    for (int k = 0; k < 8; ++k) acc[k] = 0.f;
    float dpart = 0.f;

    for (int c = start; c < end; c += 64) {
        int j = c + lane;
        float e = 0.f;
        int src = 0;   // padded lanes use src=0 (safe row), e=0
        if (j < end) {
            src = csr_src[j];
            float s = asl + anb[src];
            s = (s >= 0.f) ? s : NEG_SLOPE * s;
            e = __expf(s);
        }
        dpart += e;
        int cnt = end - c;
        if (cnt > 64) cnt = 64;
        int iters = (cnt + 3) >> 2;

        float w0 = __shfl(e, q, 64);
        int s0 = __shfl(src, q, 64);
        uint4 f0 = fb[(size_t)s0 * 16 + l16];
        float w1 = 0.f;
        uint4 f1 = f0;
        if (iters > 1) {
            w1 = __shfl(e, 4 + q, 64);
            int s1 = __shfl(src, 4 + q, 64);
            f1 = fb[(size_t)s1 * 16 + l16];
        }

        for (int i2 = 0; i2 < iters; ++i2) {
            float w2 = 0.f;
            uint4 f2 = f0;
            if (i2 + 2 < iters) {
                int idx = (i2 + 2) * 4 + q;
                w2 = __shfl(e, idx, 64);
                int s2 = __shfl(src, idx, 64);
                f2 = fb[(size_t)s2 * 16 + l16];
            }
#pragma unroll
            for (int k = 0; k < 4; ++k) {
                unsigned int u = (&f0.x)[k];
                float lo = __uint_as_float(u << 16);
                float hi = __uint_as_float(u & 0xffff0000u);
                acc[2 * k]     += w0 * lo;
                acc[2 * k + 1] += w0 * hi;
            }
            w0 = w1; f0 = f1;
            w1 = w2; f1 = f2;
        }
    }

#pragma unroll
    for (int k = 0; k < 8; ++k) {
        acc[k] += __shfl_xor(acc[k], 16, 64);
        acc[k] += __shfl_xor(acc[k], 32, 64);
    }
    float denom = dpart;
#pragma unroll
    for (int off = 32; off > 0; off >>= 1) denom += __shfl_xor(denom, off, 64);

    if (q == 0) {
        float inv = (end > start) ? 1.f / denom : 0.f;
        uint4 rb = reinterpret_cast<const uint4*>(
            resid_b16 + ((size_t)b * N_NODES + n) * DIM)[l16];
        float4 o0, o1;
        unsigned int u = rb.x;
        o0.x = fmaxf(acc[0] * inv + __uint_as_float(u << 16), 0.f);
        o0.y = fmaxf(acc[1] * inv + __uint_as_float(u & 0xffff0000u), 0.f);
        u = rb.y;
        o0.z = fmaxf(acc[2] * inv + __uint_as_float(u << 16), 0.f);
        o0.w = fmaxf(acc[3] * inv + __uint_as_float(u & 0xffff0000u), 0.f);
        u = rb.z;
        o1.x = fmaxf(acc[4] * inv + __uint_as_float(u << 16), 0.f);
        o1.y = fmaxf(acc[5] * inv + __uint_as_float(u & 0xffff0000u), 0.f);
        u = rb.w;
        o1.z = fmaxf(acc[6] * inv + __uint_as_float(u << 16), 0.f);
        o1.w = fmaxf(acc[7] * inv + __uint_as_float(u & 0xffff0000u), 0.f);
        float4* po = reinterpret_cast<float4*>(out + (size_t)n * (2 * DIM) + b * DIM);
        po[l16 * 2] = o0;
        po[l16 * 2 + 1] = o1;
    }
}

// ---------------- per-graph sum pooling ----------------
__device__ int lower_bound_dev(const int* __restrict__ a, int n, int key) {
    int lo = 0, hi = n;
    while (lo < hi) {
        int mid = (lo + hi) >> 1;
        if (a[mid] < key) lo = mid + 1;
        else hi = mid;
    }
    return lo;
}

__global__ __launch_bounds__(256) void pool_graphs(
    const float* __restrict__ h, const int* __restrict__ gids,
    float* __restrict__ phis) {
    const int g = blockIdx.x;
    const int chunk = blockIdx.y;
    const int tid = threadIdx.x;
    int lo = lower_bound_dev(gids, N_NODES, g);
    int hi = lower_bound_dev(gids, N_NODES, g + 1);
    float acc = 0.f;
    for (int n = lo + chunk; n < hi; n += 16) acc += h[(size_t)n * (2 * DIM) + tid];
    if (acc != 0.f) atomicAdd(&phis[(size_t)g * (2 * DIM) + tid], acc);
}

extern "C" void kernel_launch(void* const* d_in, const int* in_sizes, int n_in,
                              void* d_out, int out_size, void* d_ws, size_t ws_size,
                              hipStream_t stream) {
    const float* x    = (const float*)d_in[0];
    const int* esrc   = (const int*)d_in[1];
    const int* edst   = (const int*)d_in[2];
    const int* gids   = (const int*)d_in[3];
    const float* Wfc  = (const float*)d_in[4];
    const float* bfc  = (const float*)d_in[5];
    const float* wl   = (const float*)d_in[6];
    const float* wr   = (const float*)d_in[7];
    const float* Wres = (const float*)d_in[8];
    float* out = (float*)d_out;

    char* ws = (char*)d_ws;
    unsigned short* resid_b16 = (unsigned short*)(ws + 0);
    float* a_self  = (float*)(ws + 5120000);
    float* a_nb    = (float*)(ws + 5200000);
    int*   deg     = (int*)(ws + 5280000);
    int*   rowptr  = (int*)(ws + 5320000);
    int*   bar     = (int*)(ws + 5360008);
    int*   csr_src = (int*)(ws + 5360032);
    unsigned short* feat_b16 = (unsigned short*)(ws + 7920032);
    int*   bh      = (int*)(ws + 13040032);

    float* phis = out + (size_t)N_NODES * 2 * DIM;

    // zero the grid-barrier counters (ws is poisoned before every call)
    hipMemsetAsync(bar, 0, 16, stream);

    gemm_mfma<<<dim3((N_NODES + 63) / 64, 4), 256, 0, stream>>>(
        x, Wfc, bfc, Wres, wl, wr, resid_b16, feat_b16, a_self, a_nb);

    csr_fused<<<NB_CSR, 1024, 0, stream>>>(
        (const int4*)esrc, (const int4*)edst, bh, deg, rowptr, csr_src, phis, bar);

    aggregate<<<dim3(2500, 2), 256, 0, stream>>>(
        feat_b16, resid_b16, a_self, a_nb, rowptr, csr_src, out);
    pool_graphs<<<dim3(N_GRAPHS, 16), 256, 0, stream>>>(out, gids, phis);
}